// Round 2
// baseline (1147.589 us; speedup 1.0000x reference)
//
#include <hip/hip_runtime.h>

// CrossAttention: B=8, C=256, H=W=64, N=4096
// split_w3 -> proj_kernel (hoisted gather, PROW=66) -> attn_kernel
// (flash, padded-stride LDS, early-issue staging, 256-thr blocks).

#define C_DIM 256
#define N_DIM 4096

using f32x4 = __attribute__((ext_vector_type(4))) float;
using s16x8 = __attribute__((ext_vector_type(8))) short;

__device__ __forceinline__ unsigned short f2bf(float f) {
  unsigned int u = __builtin_bit_cast(unsigned int, f);
  u += 0x7FFFu + ((u >> 16) & 1u);   // RNE
  return (unsigned short)(u >> 16);
}
__device__ __forceinline__ float bf2f(unsigned short h) {
  unsigned int u = ((unsigned int)h) << 16;
  return __builtin_bit_cast(float, u);
}
__device__ __forceinline__ f32x4 mfma16(s16x8 a, s16x8 b, f32x4 c) {
  return __builtin_amdgcn_mfma_f32_16x16x32_bf16(a, b, c, 0, 0, 0);
}

// ---------------- kernel 1: split W into bf16 hi/lo planes ----------------
__global__ __launch_bounds__(256) void split_w3(const float* __restrict__ wq,
                                                const float* __restrict__ wk,
                                                const float* __restrict__ wv,
                                                unsigned short* __restrict__ dst) {
  int i = blockIdx.x * 256 + threadIdx.x;  // 0..65535
  int m = blockIdx.y;                      // 0..2
  const float* w = (m == 0) ? wq : ((m == 1) ? wk : wv);
  float x = w[i];
  unsigned short h = f2bf(x);
  unsigned short l = f2bf(x - bf2f(h));
  dst[m * 131072 + i] = h;
  dst[m * 131072 + 65536 + i] = l;
}

// ---------------- kernel 2: projections ----------------
// p=0: q=Wq*x1+bq -> qt_hi/lo [b][n][c];  p=1: k -> kt_hi/lo [b][n][c];
// p=2: v=Wv*x2+bv -> vv [b][c][n] bf16.
// X B-fragments gathered ONCE per wave (hoisted out of ot loop).
#define PROW 66   // 132B rows: gather lanes land on disjoint bank octets
__global__ __launch_bounds__(256) void proj_kernel(
    const float* __restrict__ x1, const float* __restrict__ x2,
    const unsigned short* __restrict__ wsp,
    const float* __restrict__ bq, const float* __restrict__ bk, const float* __restrict__ bv,
    unsigned short* __restrict__ qt_hi, unsigned short* __restrict__ qt_lo,
    unsigned short* __restrict__ kt_hi, unsigned short* __restrict__ kt_lo,
    unsigned short* __restrict__ vv) {
  __shared__ __align__(16) unsigned short sxh[256 * PROW];
  __shared__ __align__(16) unsigned short sxl[256 * PROW];
  const int t = threadIdx.x;
  const int n0 = blockIdx.x * 64;
  const int b = blockIdx.y;
  const int p = blockIdx.z;
  const float* x = (p == 0) ? x1 : x2;
  const float* bias = (p == 0) ? bq : ((p == 1) ? bk : bv);
  const unsigned short* wh = wsp + p * 131072;
  const unsigned short* wl = wh + 65536;

  // stage x tile [256c][64n] fp32 -> LDS bf16 hi/lo
  for (int it = 0; it < 16; ++it) {
    int chunk = t + 256 * it;      // 0..4095 float4 chunks
    int row = chunk >> 4, n4 = chunk & 15;
    float4 v4 = *((const float4*)(x + ((size_t)b * 256 + row) * 4096 + n0) + n4);
    float vals[4] = {v4.x, v4.y, v4.z, v4.w};
    unsigned short hh[4], ll[4];
    #pragma unroll
    for (int j = 0; j < 4; ++j) {
      hh[j] = f2bf(vals[j]);
      ll[j] = f2bf(vals[j] - bf2f(hh[j]));
    }
    int base = row * PROW + n4 * 4;
    *(ushort4*)(sxh + base) = make_ushort4(hh[0], hh[1], hh[2], hh[3]);
    *(ushort4*)(sxl + base) = make_ushort4(ll[0], ll[1], ll[2], ll[3]);
  }
  __syncthreads();

  const int w = t >> 6;
  const int lane = t & 63;
  const int li = lane & 15;
  const int lg = lane >> 4;
  const int nloc = w * 16 + li;       // this wave's n column (B-frag col)

  // hoisted B-fragment gather: depends only on (cs, lane)
  s16x8 xfh[8], xfl[8];
  #pragma unroll
  for (int cs = 0; cs < 8; ++cs) {
    #pragma unroll
    for (int jj = 0; jj < 8; ++jj) {
      int cc = cs * 32 + lg * 8 + jj;
      xfh[cs][jj] = (short)sxh[cc * PROW + nloc];
      xfl[cs][jj] = (short)sxl[cc * PROW + nloc];
    }
  }

  for (int ot = 0; ot < 16; ++ot) {
    f32x4 acc = 0.0f;
    const int ofr = ot * 16 + li;     // A-frag row (output channel o)
    #pragma unroll
    for (int cs = 0; cs < 8; ++cs) {
      s16x8 wfh = *(const s16x8*)(wh + ofr * 256 + cs * 32 + lg * 8);
      s16x8 wfl = *(const s16x8*)(wl + ofr * 256 + cs * 32 + lg * 8);
      acc = mfma16(wfh, xfh[cs], acc);   // hi*hi
      acc = mfma16(wfh, xfl[cs], acc);   // hi*lo
      acc = mfma16(wfl, xfh[cs], acc);   // lo*hi
    }
    int n = n0 + nloc;
    if (p == 2) {
      #pragma unroll
      for (int r = 0; r < 4; ++r) {
        int o = ot * 16 + lg * 4 + r;
        vv[((size_t)b * 256 + o) * 4096 + n] = f2bf(acc[r] + bias[o]);
      }
    } else {
      ushort4 ph, pl;
      unsigned short* dh = (p == 0) ? qt_hi : kt_hi;
      unsigned short* dl = (p == 0) ? qt_lo : kt_lo;
      unsigned short hh[4], ll[4];
      #pragma unroll
      for (int r = 0; r < 4; ++r) {
        int o = ot * 16 + lg * 4 + r;
        float val = acc[r] + bias[o];
        hh[r] = f2bf(val);
        ll[r] = f2bf(val - bf2f(hh[r]));
      }
      ph = make_ushort4(hh[0], hh[1], hh[2], hh[3]);
      pl = make_ushort4(ll[0], ll[1], ll[2], ll[3]);
      size_t idx = ((size_t)b * 4096 + n) * 256 + ot * 16 + lg * 4;
      *(ushort4*)(dh + idx) = ph;
      *(ushort4*)(dl + idx) = pl;
    }
  }
}

// ---------------- kernel 3: flash attention ----------------
// grid (8 batches, 64 qblocks), 256 threads (4 waves x 16 queries each).
// Padded-stride LDS: K rows 528B (slot walks row&7), V rows 80B (slot 5c&7).
// Early-issue staging: loads for kt+1 issued before compute of kt (T14).
#define KROWB 528   // bytes per K row in LDS
#define VROWB 80    // bytes per V row in LDS
#define NT 128      // 4096/32 key tiles

__global__ __launch_bounds__(256, 2) void attn_kernel(
    const unsigned short* __restrict__ qt_hi, const unsigned short* __restrict__ qt_lo,
    const unsigned short* __restrict__ kt_hi, const unsigned short* __restrict__ kt_lo,
    const unsigned short* __restrict__ vv, float* __restrict__ out) {
  __shared__ __align__(16) unsigned short skh[32 * KROWB / 2];
  __shared__ __align__(16) unsigned short skl[32 * KROWB / 2];
  __shared__ __align__(16) unsigned short sv[256 * VROWB / 2];

  const int tid = threadIdx.x;
  const int b = blockIdx.x;                 // batch
  const int w = tid >> 6;
  const int lane = tid & 63;
  const int li = lane & 15;
  const int lg = lane >> 4;
  const int q0 = blockIdx.y * 64 + w * 16;

  // Q fragments: 16 queries x 256 channels, hi/lo
  s16x8 qh[8], ql[8];
  {
    const size_t qrow = ((size_t)b * N_DIM + q0 + li) * C_DIM;
    #pragma unroll
    for (int cs = 0; cs < 8; ++cs) {
      qh[cs] = *(const s16x8*)(qt_hi + qrow + cs * 32 + lg * 8);
      ql[cs] = *(const s16x8*)(qt_lo + qrow + cs * 32 + lg * 8);
    }
  }

  f32x4 acc[16];
  #pragma unroll
  for (int ct = 0; ct < 16; ++ct) acc[ct] = 0.0f;
  float m_run = -1e30f, l_run = 0.f;

  int4 rkh[4], rkl[4], rv[4];
#define LOADT(KT)                                                        \
  {                                                                      \
    int k0_ = (KT) * 32;                                                 \
    _Pragma("unroll")                                                    \
    for (int j = 0; j < 4; ++j) {                                        \
      int chunk = j * 256 + tid;                                         \
      int row = chunk >> 5, o16 = chunk & 31;                            \
      size_t g = ((size_t)b * N_DIM + k0_ + row) * C_DIM + o16 * 8;      \
      rkh[j] = *(const int4*)(kt_hi + g);                                \
      rkl[j] = *(const int4*)(kt_lo + g);                                \
      int c = chunk >> 2, o4 = chunk & 3;                                \
      size_t gv = ((size_t)b * C_DIM + c) * N_DIM + k0_ + o4 * 8;        \
      rv[j] = *(const int4*)(vv + gv);                                   \
    }                                                                    \
  }

  LOADT(0)

  for (int kt = 0; kt < NT; ++kt) {
    __syncthreads();                    // previous compute done with LDS
    #pragma unroll
    for (int j = 0; j < 4; ++j) {
      int chunk = j * 256 + tid;
      int row = chunk >> 5, o16 = chunk & 31;
      *(int4*)((char*)skh + row * KROWB + o16 * 16) = rkh[j];
      *(int4*)((char*)skl + row * KROWB + o16 * 16) = rkl[j];
      int c = chunk >> 2, o4 = chunk & 3;
      *(int4*)((char*)sv + c * VROWB + o4 * 16) = rv[j];
    }
    __syncthreads();                    // tile ready
    if (kt + 1 < NT) LOADT(kt + 1)      // issue next-tile loads (overlap compute)

    // QK^T (swapped, hi/lo 3-term)
    f32x4 st[2];
    st[0] = 0.0f; st[1] = 0.0f;
    __builtin_amdgcn_s_setprio(1);
    #pragma unroll
    for (int cs = 0; cs < 8; ++cs) {
      #pragma unroll
      for (int t2 = 0; t2 < 2; ++t2) {
        int row = t2 * 16 + li;
        int off = row * KROWB + cs * 64 + lg * 16;
        s16x8 kh = *(const s16x8*)((const char*)skh + off);
        s16x8 kl = *(const s16x8*)((const char*)skl + off);
        st[t2] = mfma16(kh, qh[cs], st[t2]);
        st[t2] = mfma16(kh, ql[cs], st[t2]);
        st[t2] = mfma16(kl, qh[cs], st[t2]);
      }
    }
    __builtin_amdgcn_s_setprio(0);

    // online softmax (defer-max, THR=8)
    float s0 = st[0][0], s1 = st[0][1], s2 = st[0][2], s3 = st[0][3];
    float s4 = st[1][0], s5 = st[1][1], s6 = st[1][2], s7 = st[1][3];
    float tmax = fmaxf(fmaxf(fmaxf(s0, s1), fmaxf(s2, s3)),
                       fmaxf(fmaxf(s4, s5), fmaxf(s6, s7)));
    tmax = fmaxf(tmax, __shfl_xor(tmax, 16));
    tmax = fmaxf(tmax, __shfl_xor(tmax, 32));
    if (tmax > m_run + 8.0f) {
      float sc = __expf(m_run - tmax);
      m_run = tmax;
      l_run *= sc;
      #pragma unroll
      for (int ct = 0; ct < 16; ++ct) {
        acc[ct][0] *= sc; acc[ct][1] *= sc; acc[ct][2] *= sc; acc[ct][3] *= sc;
      }
    }
    float e0 = __expf(s0 - m_run), e1 = __expf(s1 - m_run);
    float e2 = __expf(s2 - m_run), e3 = __expf(s3 - m_run);
    float e4 = __expf(s4 - m_run), e5 = __expf(s5 - m_run);
    float e6 = __expf(s6 - m_run), e7 = __expf(s7 - m_run);
    float ts = ((e0 + e1) + (e2 + e3)) + ((e4 + e5) + (e6 + e7));
    ts += __shfl_xor(ts, 16);
    ts += __shfl_xor(ts, 32);
    l_run += ts;

    // pack P -> bf16 dwords; permute into 16x16x32 B-frag
    unsigned int W00 = (unsigned int)f2bf(e0) | ((unsigned int)f2bf(e1) << 16);
    unsigned int W01 = (unsigned int)f2bf(e2) | ((unsigned int)f2bf(e3) << 16);
    unsigned int W10 = (unsigned int)f2bf(e4) | ((unsigned int)f2bf(e5) << 16);
    unsigned int W11 = (unsigned int)f2bf(e6) | ((unsigned int)f2bf(e7) << 16);
    int srcA = li + 32 * (lg & 1);
    int srcB = srcA + 16;
    unsigned int a00 = __shfl(W00, srcA), a01 = __shfl(W01, srcA);
    unsigned int a10 = __shfl(W10, srcA), a11 = __shfl(W11, srcA);
    unsigned int b00 = __shfl(W00, srcB), b01 = __shfl(W01, srcB);
    unsigned int b10 = __shfl(W10, srcB), b11 = __shfl(W11, srcB);
    bool h2 = (lg >> 1) != 0;
    union { unsigned int u[4]; s16x8 v; } pu;
    pu.u[0] = h2 ? a10 : a00;
    pu.u[1] = h2 ? a11 : a01;
    pu.u[2] = h2 ? b10 : b00;
    pu.u[3] = h2 ? b11 : b01;

    // PV: acc[ct] += V_tile * P^T
    __builtin_amdgcn_s_setprio(1);
    #pragma unroll
    for (int ct = 0; ct < 16; ++ct) {
      int c = ct * 16 + li;
      s16x8 vf = *(const s16x8*)((const char*)sv + c * VROWB + lg * 16);
      acc[ct] = mfma16(vf, pu.v, acc[ct]);
    }
    __builtin_amdgcn_s_setprio(0);
  }

  // epilogue: normalize and store out[b][c][n] fp32
  float inv = 1.0f / l_run;
  #pragma unroll
  for (int ct = 0; ct < 16; ++ct) {
    #pragma unroll
    for (int r = 0; r < 4; ++r) {
      int c = ct * 16 + lg * 4 + r;
      out[((size_t)b * C_DIM + c) * N_DIM + q0 + li] = acc[ct][r] * inv;
    }
  }
#undef LOADT
}

extern "C" void kernel_launch(void* const* d_in, const int* in_sizes, int n_in,
                              void* d_out, int out_size, void* d_ws, size_t ws_size,
                              hipStream_t stream) {
  const float* x1 = (const float*)d_in[0];
  const float* x2 = (const float*)d_in[1];
  const float* Wq = (const float*)d_in[2];
  const float* bq = (const float*)d_in[3];
  const float* Wk = (const float*)d_in[4];
  const float* bk = (const float*)d_in[5];
  const float* Wv = (const float*)d_in[6];
  const float* bv = (const float*)d_in[7];
  float* out = (float*)d_out;

  char* ws = (char*)d_ws;
  const size_t SZ = (size_t)8 * 4096 * 256 * 2;  // 16.78 MB per bf16 plane
  unsigned short* qt_hi = (unsigned short*)(ws + 0 * SZ);
  unsigned short* qt_lo = (unsigned short*)(ws + 1 * SZ);
  unsigned short* kt_hi = (unsigned short*)(ws + 2 * SZ);
  unsigned short* kt_lo = (unsigned short*)(ws + 3 * SZ);
  unsigned short* vv    = (unsigned short*)(ws + 4 * SZ);
  unsigned short* wsp   = (unsigned short*)(ws + 5 * SZ);  // 3*2*65536 shorts
  // requires ws_size >= 5*SZ + 786432 = 84,672,512 bytes

  split_w3<<<dim3(256, 3), 256, 0, stream>>>(Wq, Wk, Wv, wsp);
  proj_kernel<<<dim3(64, 8, 3), 256, 0, stream>>>(x1, x2, wsp, bq, bk, bv,
                                                  qt_hi, qt_lo, kt_hi, kt_lo, vv);
  attn_kernel<<<dim3(8, 64), 256, 0, stream>>>(qt_hi, qt_lo, kt_hi, kt_lo, vv, out);
}

// Round 3
// 476.257 us; speedup vs baseline: 2.4096x; 2.4096x over previous
//
#include <hip/hip_runtime.h>

// CrossAttention: B=8, C=256, H=W=64, N=4096
// split_w3 -> proj_kernel (hoisted gather) -> attn_kernel (flash, dbuf LDS via
// global_load_lds with pre-swizzled source, conflict-free K and V swizzles).

#define C_DIM 256
#define N_DIM 4096

using f32x4 = __attribute__((ext_vector_type(4))) float;
using s16x8 = __attribute__((ext_vector_type(8))) short;

__device__ __forceinline__ unsigned short f2bf(float f) {
  unsigned int u = __builtin_bit_cast(unsigned int, f);
  u += 0x7FFFu + ((u >> 16) & 1u);   // RNE
  return (unsigned short)(u >> 16);
}
__device__ __forceinline__ float bf2f(unsigned short h) {
  unsigned int u = ((unsigned int)h) << 16;
  return __builtin_bit_cast(float, u);
}
__device__ __forceinline__ f32x4 mfma16(s16x8 a, s16x8 b, f32x4 c) {
  return __builtin_amdgcn_mfma_f32_16x16x32_bf16(a, b, c, 0, 0, 0);
}
__device__ __forceinline__ void gload_lds16(const unsigned short* g, void* l) {
  __builtin_amdgcn_global_load_lds(
      (const __attribute__((address_space(1))) unsigned int*)g,
      (__attribute__((address_space(3))) unsigned int*)l, 16, 0, 0);
}

// ---------------- kernel 1: split W into bf16 hi/lo planes ----------------
__global__ __launch_bounds__(256) void split_w3(const float* __restrict__ wq,
                                                const float* __restrict__ wk,
                                                const float* __restrict__ wv,
                                                unsigned short* __restrict__ dst) {
  int i = blockIdx.x * 256 + threadIdx.x;  // 0..65535
  int m = blockIdx.y;                      // 0..2
  const float* w = (m == 0) ? wq : ((m == 1) ? wk : wv);
  float x = w[i];
  unsigned short h = f2bf(x);
  unsigned short l = f2bf(x - bf2f(h));
  dst[m * 131072 + i] = h;
  dst[m * 131072 + 65536 + i] = l;
}

// ---------------- kernel 2: projections ----------------
// p=0: q=Wq*x1+bq -> qt_hi/lo [b][n][c];  p=1: k -> kt_hi/lo [b][n][c];
// p=2: v=Wv*x2+bv -> vv [b][c][n] bf16.
#define PROW 66
__global__ __launch_bounds__(256) void proj_kernel(
    const float* __restrict__ x1, const float* __restrict__ x2,
    const unsigned short* __restrict__ wsp,
    const float* __restrict__ bq, const float* __restrict__ bk, const float* __restrict__ bv,
    unsigned short* __restrict__ qt_hi, unsigned short* __restrict__ qt_lo,
    unsigned short* __restrict__ kt_hi, unsigned short* __restrict__ kt_lo,
    unsigned short* __restrict__ vv) {
  __shared__ __align__(16) unsigned short sxh[256 * PROW];
  __shared__ __align__(16) unsigned short sxl[256 * PROW];
  const int t = threadIdx.x;
  const int n0 = blockIdx.x * 64;
  const int b = blockIdx.y;
  const int p = blockIdx.z;
  const float* x = (p == 0) ? x1 : x2;
  const float* bias = (p == 0) ? bq : ((p == 1) ? bk : bv);
  const unsigned short* wh = wsp + p * 131072;
  const unsigned short* wl = wh + 65536;

  for (int it = 0; it < 16; ++it) {
    int chunk = t + 256 * it;
    int row = chunk >> 4, n4 = chunk & 15;
    float4 v4 = *((const float4*)(x + ((size_t)b * 256 + row) * 4096 + n0) + n4);
    float vals[4] = {v4.x, v4.y, v4.z, v4.w};
    unsigned short hh[4], ll[4];
    #pragma unroll
    for (int j = 0; j < 4; ++j) {
      hh[j] = f2bf(vals[j]);
      ll[j] = f2bf(vals[j] - bf2f(hh[j]));
    }
    int base = row * PROW + n4 * 4;
    *(ushort4*)(sxh + base) = make_ushort4(hh[0], hh[1], hh[2], hh[3]);
    *(ushort4*)(sxl + base) = make_ushort4(ll[0], ll[1], ll[2], ll[3]);
  }
  __syncthreads();

  const int w = t >> 6;
  const int lane = t & 63;
  const int li = lane & 15;
  const int lg = lane >> 4;
  const int nloc = w * 16 + li;

  s16x8 xfh[8], xfl[8];
  #pragma unroll
  for (int cs = 0; cs < 8; ++cs) {
    #pragma unroll
    for (int jj = 0; jj < 8; ++jj) {
      int cc = cs * 32 + lg * 8 + jj;
      xfh[cs][jj] = (short)sxh[cc * PROW + nloc];
      xfl[cs][jj] = (short)sxl[cc * PROW + nloc];
    }
  }

  for (int ot = 0; ot < 16; ++ot) {
    f32x4 acc = 0.0f;
    const int ofr = ot * 16 + li;
    #pragma unroll
    for (int cs = 0; cs < 8; ++cs) {
      s16x8 wfh = *(const s16x8*)(wh + ofr * 256 + cs * 32 + lg * 8);
      s16x8 wfl = *(const s16x8*)(wl + ofr * 256 + cs * 32 + lg * 8);
      acc = mfma16(wfh, xfh[cs], acc);
      acc = mfma16(wfh, xfl[cs], acc);
      acc = mfma16(wfl, xfh[cs], acc);
    }
    int n = n0 + nloc;
    if (p == 2) {
      #pragma unroll
      for (int r = 0; r < 4; ++r) {
        int o = ot * 16 + lg * 4 + r;
        vv[((size_t)b * 256 + o) * 4096 + n] = f2bf(acc[r] + bias[o]);
      }
    } else {
      unsigned short* dh = (p == 0) ? qt_hi : kt_hi;
      unsigned short* dl = (p == 0) ? qt_lo : kt_lo;
      unsigned short hh[4], ll[4];
      #pragma unroll
      for (int r = 0; r < 4; ++r) {
        int o = ot * 16 + lg * 4 + r;
        float val = acc[r] + bias[o];
        hh[r] = f2bf(val);
        ll[r] = f2bf(val - bf2f(hh[r]));
      }
      size_t idx = ((size_t)b * 4096 + n) * 256 + ot * 16 + lg * 4;
      *(ushort4*)(dh + idx) = make_ushort4(hh[0], hh[1], hh[2], hh[3]);
      *(ushort4*)(dl + idx) = make_ushort4(ll[0], ll[1], ll[2], ll[3]);
    }
  }
}

// ---------------- kernel 3: flash attention ----------------
// 512 threads (8 waves x 16 queries), grid (8, 32) = 1 block/CU.
// Double-buffered LDS (2 x 48KB) staged via global_load_lds with
// pre-swizzled per-lane global source; one barrier per iteration.
// K slot: s16 = o16 ^ (row&7)   (bijective; conflict-free read phases)
// V slot: s4  = o4  ^ ((c>>1)&3) (conflict-free read/write phases)
#define NT 128
#define KHOFF 0
#define KLOFF 16384
#define VOFF  32768
#define BUFSZ 49152

__global__ __launch_bounds__(512, 2) void attn_kernel(
    const unsigned short* __restrict__ qt_hi, const unsigned short* __restrict__ qt_lo,
    const unsigned short* __restrict__ kt_hi, const unsigned short* __restrict__ kt_lo,
    const unsigned short* __restrict__ vv, float* __restrict__ out) {
  __shared__ __align__(16) char lds[2 * BUFSZ];

  const int tid = threadIdx.x;
  const int b = blockIdx.x;
  const int w = tid >> 6;
  const int lane = tid & 63;
  const int li = lane & 15;
  const int lg = lane >> 4;
  const int q0 = blockIdx.y * 128 + w * 16;

  // Q fragments: 16 queries x 256 channels, hi/lo
  s16x8 qh[8], ql[8];
  {
    const size_t qrow = ((size_t)b * N_DIM + q0 + li) * C_DIM;
    #pragma unroll
    for (int cs = 0; cs < 8; ++cs) {
      qh[cs] = *(const s16x8*)(qt_hi + qrow + cs * 32 + lg * 8);
      ql[cs] = *(const s16x8*)(qt_lo + qrow + cs * 32 + lg * 8);
    }
  }

  f32x4 acc[16];
  #pragma unroll
  for (int ct = 0; ct < 16; ++ct) acc[ct] = 0.0f;
  float m_run = -1e30f, l_run = 0.f;

  // async stage of one 32-key tile into buffer BUF (6 global_load_lds / wave)
#define STAGE(BUF, KT)                                                        \
  {                                                                           \
    int k0_ = (KT) * 32;                                                      \
    char* bb = lds + (BUF) * BUFSZ;                                           \
    _Pragma("unroll")                                                         \
    for (int j = 0; j < 2; ++j) {                                             \
      int l = w * 128 + j * 64 + lane;                                        \
      int row = l >> 5, s16 = l & 31;                                         \
      int o16 = s16 ^ (row & 7);                                              \
      size_t gk = ((size_t)b * N_DIM + k0_ + row) * C_DIM + o16 * 8;          \
      int dstb = (w * 128 + j * 64) * 16;                                     \
      gload_lds16(kt_hi + gk, bb + KHOFF + dstb);                             \
      gload_lds16(kt_lo + gk, bb + KLOFF + dstb);                             \
      int c = l >> 2, s4 = l & 3;                                             \
      int o4 = s4 ^ ((c >> 1) & 3);                                           \
      size_t gv = ((size_t)b * C_DIM + c) * N_DIM + k0_ + o4 * 8;             \
      gload_lds16(vv + gv, bb + VOFF + dstb);                                 \
    }                                                                         \
  }

  STAGE(0, 0)
  int cur = 0;

  for (int kt = 0; kt < NT; ++kt) {
    __syncthreads();                 // drains vmcnt: buf[cur] ready; prev compute done
    if (kt + 1 < NT) STAGE(cur ^ 1, kt + 1)
    const char* bb = lds + cur * BUFSZ;

    // QK^T (swapped, hi/lo 3-term)
    f32x4 st[2];
    st[0] = 0.0f; st[1] = 0.0f;
    __builtin_amdgcn_s_setprio(1);
    #pragma unroll
    for (int cs = 0; cs < 8; ++cs) {
      #pragma unroll
      for (int t2 = 0; t2 < 2; ++t2) {
        int row = t2 * 16 + li;
        int off = row * 512 + (((cs * 4 + lg) ^ (row & 7)) * 16);
        s16x8 kh = *(const s16x8*)(bb + KHOFF + off);
        s16x8 kl = *(const s16x8*)(bb + KLOFF + off);
        st[t2] = mfma16(kh, qh[cs], st[t2]);
        st[t2] = mfma16(kh, ql[cs], st[t2]);
        st[t2] = mfma16(kl, qh[cs], st[t2]);
      }
    }
    __builtin_amdgcn_s_setprio(0);

    // online softmax (defer-max, THR=8)
    float s0 = st[0][0], s1 = st[0][1], s2 = st[0][2], s3 = st[0][3];
    float s4 = st[1][0], s5 = st[1][1], s6 = st[1][2], s7 = st[1][3];
    float tmax = fmaxf(fmaxf(fmaxf(s0, s1), fmaxf(s2, s3)),
                       fmaxf(fmaxf(s4, s5), fmaxf(s6, s7)));
    tmax = fmaxf(tmax, __shfl_xor(tmax, 16));
    tmax = fmaxf(tmax, __shfl_xor(tmax, 32));
    if (tmax > m_run + 8.0f) {
      float sc = __expf(m_run - tmax);
      m_run = tmax;
      l_run *= sc;
      #pragma unroll
      for (int ct = 0; ct < 16; ++ct) {
        acc[ct][0] *= sc; acc[ct][1] *= sc; acc[ct][2] *= sc; acc[ct][3] *= sc;
      }
    }
    float e0 = __expf(s0 - m_run), e1 = __expf(s1 - m_run);
    float e2 = __expf(s2 - m_run), e3 = __expf(s3 - m_run);
    float e4 = __expf(s4 - m_run), e5 = __expf(s5 - m_run);
    float e6 = __expf(s6 - m_run), e7 = __expf(s7 - m_run);
    float ts = ((e0 + e1) + (e2 + e3)) + ((e4 + e5) + (e6 + e7));
    ts += __shfl_xor(ts, 16);
    ts += __shfl_xor(ts, 32);
    l_run += ts;

    // pack P -> bf16 dwords; permute into 16x16x32 B-frag
    unsigned int W00 = (unsigned int)f2bf(e0) | ((unsigned int)f2bf(e1) << 16);
    unsigned int W01 = (unsigned int)f2bf(e2) | ((unsigned int)f2bf(e3) << 16);
    unsigned int W10 = (unsigned int)f2bf(e4) | ((unsigned int)f2bf(e5) << 16);
    unsigned int W11 = (unsigned int)f2bf(e6) | ((unsigned int)f2bf(e7) << 16);
    int srcA = li + 32 * (lg & 1);
    int srcB = srcA + 16;
    unsigned int a00 = __shfl(W00, srcA), a01 = __shfl(W01, srcA);
    unsigned int a10 = __shfl(W10, srcA), a11 = __shfl(W11, srcA);
    unsigned int b00 = __shfl(W00, srcB), b01 = __shfl(W01, srcB);
    unsigned int b10 = __shfl(W10, srcB), b11 = __shfl(W11, srcB);
    bool h2 = (lg >> 1) != 0;
    union { unsigned int u[4]; s16x8 v; } pu;
    pu.u[0] = h2 ? a10 : a00;
    pu.u[1] = h2 ? a11 : a01;
    pu.u[2] = h2 ? b10 : b00;
    pu.u[3] = h2 ? b11 : b01;

    // PV: acc[ct] += V_tile * P^T
    __builtin_amdgcn_s_setprio(1);
    #pragma unroll
    for (int ct = 0; ct < 16; ++ct) {
      int c = ct * 16 + li;
      int off = c * 64 + ((lg ^ ((c >> 1) & 3)) * 16);
      s16x8 vf = *(const s16x8*)(bb + VOFF + off);
      acc[ct] = mfma16(vf, pu.v, acc[ct]);
    }
    __builtin_amdgcn_s_setprio(0);

    cur ^= 1;
  }

  // epilogue: normalize and store out[b][c][n] fp32
  float inv = 1.0f / l_run;
  #pragma unroll
  for (int ct = 0; ct < 16; ++ct) {
    #pragma unroll
    for (int r = 0; r < 4; ++r) {
      int c = ct * 16 + lg * 4 + r;
      out[((size_t)b * C_DIM + c) * N_DIM + q0 + li] = acc[ct][r] * inv;
    }
  }
#undef STAGE
}

extern "C" void kernel_launch(void* const* d_in, const int* in_sizes, int n_in,
                              void* d_out, int out_size, void* d_ws, size_t ws_size,
                              hipStream_t stream) {
  const float* x1 = (const float*)d_in[0];
  const float* x2 = (const float*)d_in[1];
  const float* Wq = (const float*)d_in[2];
  const float* bq = (const float*)d_in[3];
  const float* Wk = (const float*)d_in[4];
  const float* bk = (const float*)d_in[5];
  const float* Wv = (const float*)d_in[6];
  const float* bv = (const float*)d_in[7];
  float* out = (float*)d_out;

  char* ws = (char*)d_ws;
  const size_t SZ = (size_t)8 * 4096 * 256 * 2;  // 16.78 MB per bf16 plane
  unsigned short* qt_hi = (unsigned short*)(ws + 0 * SZ);
  unsigned short* qt_lo = (unsigned short*)(ws + 1 * SZ);
  unsigned short* kt_hi = (unsigned short*)(ws + 2 * SZ);
  unsigned short* kt_lo = (unsigned short*)(ws + 3 * SZ);
  unsigned short* vv    = (unsigned short*)(ws + 4 * SZ);
  unsigned short* wsp   = (unsigned short*)(ws + 5 * SZ);  // 3*2*65536 shorts
  // requires ws_size >= 5*SZ + 786432 = 84,672,512 bytes

  split_w3<<<dim3(256, 3), 256, 0, stream>>>(Wq, Wk, Wv, wsp);
  proj_kernel<<<dim3(64, 8, 3), 256, 0, stream>>>(x1, x2, wsp, bq, bk, bv,
                                                  qt_hi, qt_lo, kt_hi, kt_lo, vv);
  attn_kernel<<<dim3(8, 32), 512, 0, stream>>>(qt_hi, qt_lo, kt_hi, kt_lo, vv, out);
}

// Round 5
// 311.246 us; speedup vs baseline: 3.6871x; 1.5302x over previous
//
#include <hip/hip_runtime.h>

// CrossAttention: B=8, C=256, H=W=64, N=4096
// Full-fp16 pipeline (fp16 mantissa 2^-11 satisfies score-precision budget
// in ONE MFMA term, vs bf16's 3-term hi/lo):
//   cvt_w3 (W->fp16) -> proj_kernel (fp16 single-term MFMA)
//   -> attn_kernel (flash, fp16 QK/PV, dbuf LDS via global_load_lds).
// K+V per batch = 4MB -> fits per-XCD L2 (batch == blockIdx.x == XCD id).

#define C_DIM 256
#define N_DIM 4096

using f32x4 = __attribute__((ext_vector_type(4))) float;
using f16x8 = __attribute__((ext_vector_type(8))) _Float16;

__device__ __forceinline__ f32x4 mfmah(f16x8 a, f16x8 b, f32x4 c) {
  return __builtin_amdgcn_mfma_f32_16x16x32_f16(a, b, c, 0, 0, 0);
}
__device__ __forceinline__ unsigned int pk2(float a, float b) {
  return __builtin_bit_cast(unsigned int, __builtin_amdgcn_cvt_pkrtz(a, b));
}
__device__ __forceinline__ void gload_lds16(const void* g, void* l) {
  __builtin_amdgcn_global_load_lds(
      (const __attribute__((address_space(1))) unsigned int*)g,
      (__attribute__((address_space(3))) unsigned int*)l, 16, 0, 0);
}

// ---------------- kernel 1: convert W to fp16 ----------------
__global__ __launch_bounds__(256) void cvt_w3(const float* __restrict__ wq,
                                              const float* __restrict__ wk,
                                              const float* __restrict__ wv,
                                              _Float16* __restrict__ dst) {
  int i = blockIdx.x * 256 + threadIdx.x;  // 0..65535
  int m = blockIdx.y;                      // 0..2
  const float* w = (m == 0) ? wq : ((m == 1) ? wk : wv);
  dst[m * 65536 + i] = (_Float16)w[i];
}

// ---------------- kernel 2: projections (fp16, single term) ----------------
// p=0: q=Wq*x1+bq -> qt [b][n][c];  p=1: k -> kt [b][n][c];
// p=2: v=Wv*x2+bv -> vv [b][c][n].  All fp16.
#define PROW 66
__global__ __launch_bounds__(256) void proj_kernel(
    const float* __restrict__ x1, const float* __restrict__ x2,
    const _Float16* __restrict__ wsp,
    const float* __restrict__ bq, const float* __restrict__ bk, const float* __restrict__ bv,
    _Float16* __restrict__ qt, _Float16* __restrict__ kt, _Float16* __restrict__ vv) {
  __shared__ __align__(16) _Float16 sx[256 * PROW];
  const int t = threadIdx.x;
  const int n0 = blockIdx.x * 64;
  const int b = blockIdx.y;
  const int p = blockIdx.z;
  const float* x = (p == 0) ? x1 : x2;
  const float* bias = (p == 0) ? bq : ((p == 1) ? bk : bv);
  const _Float16* wp = wsp + p * 65536;

  // stage x tile [256c][64n] fp32 -> LDS fp16
  for (int it = 0; it < 16; ++it) {
    int chunk = t + 256 * it;
    int row = chunk >> 4, n4 = chunk & 15;
    float4 v4 = *((const float4*)(x + ((size_t)b * 256 + row) * 4096 + n0) + n4);
    union { _Float16 h[4]; ushort4 u; } pk;
    pk.h[0] = (_Float16)v4.x; pk.h[1] = (_Float16)v4.y;
    pk.h[2] = (_Float16)v4.z; pk.h[3] = (_Float16)v4.w;
    *(ushort4*)(sx + row * PROW + n4 * 4) = pk.u;
  }
  __syncthreads();

  const int wv_ = t >> 6;
  const int lane = t & 63;
  const int li = lane & 15;
  const int lg = lane >> 4;
  const int nloc = wv_ * 16 + li;

  // hoisted B-fragment gather (depends only on cs, lane)
  f16x8 xf[8];
  #pragma unroll
  for (int cs = 0; cs < 8; ++cs) {
    #pragma unroll
    for (int jj = 0; jj < 8; ++jj)
      xf[cs][jj] = sx[(cs * 32 + lg * 8 + jj) * PROW + nloc];
  }

  const int n = n0 + nloc;
  for (int ot = 0; ot < 16; ++ot) {
    f32x4 acc = 0.0f;
    const int ofr = ot * 16 + li;
    #pragma unroll
    for (int cs = 0; cs < 8; ++cs) {
      f16x8 wf = *(const f16x8*)(wp + ofr * 256 + cs * 32 + lg * 8);
      acc = mfmah(wf, xf[cs], acc);
    }
    if (p == 2) {
      #pragma unroll
      for (int r = 0; r < 4; ++r) {
        int o = ot * 16 + lg * 4 + r;
        vv[((size_t)b * 256 + o) * 4096 + n] = (_Float16)(acc[r] + bias[o]);
      }
    } else {
      _Float16* d = (p == 0) ? qt : kt;
      union { _Float16 h[4]; ushort4 u; } pk;
      #pragma unroll
      for (int r = 0; r < 4; ++r)
        pk.h[r] = (_Float16)(acc[r] + bias[ot * 16 + lg * 4 + r]);
      *(ushort4*)(d + ((size_t)b * 4096 + n) * 256 + ot * 16 + lg * 4) = pk.u;
    }
  }
}

// ---------------- kernel 3: flash attention (fp16) ----------------
// 512 threads (8 waves x 16 queries), grid (8 batches, 32 qblocks).
// Double-buffered LDS (2 x 32KB: K 16KB + V 16KB) via global_load_lds with
// pre-swizzled per-lane global source; one barrier per iteration.
// K slot: s16 = o16 ^ (row&7); V slot: s4 = o4 ^ ((c>>1)&3)  (conflict-free).
#define NT 128
#define VOFF 16384
#define BUFSZ 32768

__global__ __launch_bounds__(512, 2) void attn_kernel(
    const _Float16* __restrict__ qtp, const _Float16* __restrict__ ktp,
    const _Float16* __restrict__ vvp, float* __restrict__ out) {
  __shared__ __align__(16) char lds[2 * BUFSZ];

  const int tid = threadIdx.x;
  const int b = blockIdx.x;
  const int w = tid >> 6;
  const int lane = tid & 63;
  const int li = lane & 15;
  const int lg = lane >> 4;
  const int q0 = blockIdx.y * 128 + w * 16;

  // Q fragments: 16 queries x 256 channels fp16 (32 VGPRs)
  f16x8 qf[8];
  {
    const size_t qrow = ((size_t)b * N_DIM + q0 + li) * C_DIM;
    #pragma unroll
    for (int cs = 0; cs < 8; ++cs)
      qf[cs] = *(const f16x8*)(qtp + qrow + cs * 32 + lg * 8);
  }

  f32x4 acc[16];
  #pragma unroll
  for (int ct = 0; ct < 16; ++ct) acc[ct] = 0.0f;
  float m_run = -1e30f, l_run = 0.f;

  // stage one 32-key tile (K 16KB + V 16KB) into buffer BUF
#define STAGE(BUF, KT)                                                        \
  {                                                                           \
    int k0_ = (KT) * 32;                                                      \
    char* bb = lds + (BUF) * BUFSZ;                                           \
    _Pragma("unroll")                                                         \
    for (int j = 0; j < 2; ++j) {                                             \
      int l = j * 512 + w * 64 + lane;                                        \
      int row = l >> 5, s16 = l & 31;                                         \
      int o16 = s16 ^ (row & 7);                                              \
      size_t gk = ((size_t)b * N_DIM + k0_ + row) * C_DIM + o16 * 8;          \
      int dstb = (j * 512 + w * 64) * 16;  /* wave-uniform LDS base */        \
      gload_lds16(ktp + gk, bb + dstb);                                       \
      int c = l >> 2, s4 = l & 3;                                             \
      int o4 = s4 ^ ((c >> 1) & 3);                                           \
      size_t gv = ((size_t)b * C_DIM + c) * N_DIM + k0_ + o4 * 8;             \
      gload_lds16(vvp + gv, bb + VOFF + dstb);                                \
    }                                                                         \
  }

  STAGE(0, 0)
  int cur = 0;

  for (int kt = 0; kt < NT; ++kt) {
    __syncthreads();                 // buf[cur] DMA drained; prev compute done
    if (kt + 1 < NT) STAGE(cur ^ 1, kt + 1)
    const char* bb = lds + cur * BUFSZ;

    // QK^T (swapped): st[t2] lane holds S[i=li][j=k0+16*t2+4*lg+r]
    f32x4 st[2];
    st[0] = 0.0f; st[1] = 0.0f;
    __builtin_amdgcn_s_setprio(1);
    #pragma unroll
    for (int cs = 0; cs < 8; ++cs) {
      #pragma unroll
      for (int t2 = 0; t2 < 2; ++t2) {
        int row = t2 * 16 + li;
        int off = row * 512 + (((cs * 4 + lg) ^ (row & 7)) * 16);
        f16x8 kf = *(const f16x8*)(bb + off);
        st[t2] = mfmah(kf, qf[cs], st[t2]);
      }
    }
    __builtin_amdgcn_s_setprio(0);

    // online softmax (defer-max, THR=8)
    float s0 = st[0][0], s1 = st[0][1], s2 = st[0][2], s3 = st[0][3];
    float s4 = st[1][0], s5 = st[1][1], s6 = st[1][2], s7 = st[1][3];
    float tmax = fmaxf(fmaxf(fmaxf(s0, s1), fmaxf(s2, s3)),
                       fmaxf(fmaxf(s4, s5), fmaxf(s6, s7)));
    tmax = fmaxf(tmax, __shfl_xor(tmax, 16));
    tmax = fmaxf(tmax, __shfl_xor(tmax, 32));
    if (tmax > m_run + 8.0f) {
      float sc = __expf(m_run - tmax);
      m_run = tmax;
      l_run *= sc;
      #pragma unroll
      for (int ct = 0; ct < 16; ++ct) {
        acc[ct][0] *= sc; acc[ct][1] *= sc; acc[ct][2] *= sc; acc[ct][3] *= sc;
      }
    }
    float e0 = __expf(s0 - m_run), e1 = __expf(s1 - m_run);
    float e2 = __expf(s2 - m_run), e3 = __expf(s3 - m_run);
    float e4 = __expf(s4 - m_run), e5 = __expf(s5 - m_run);
    float e6 = __expf(s6 - m_run), e7 = __expf(s7 - m_run);
    float ts = ((e0 + e1) + (e2 + e3)) + ((e4 + e5) + (e6 + e7));
    ts += __shfl_xor(ts, 16);
    ts += __shfl_xor(ts, 32);
    l_run += ts;

    // pack P -> fp16 dwords (v_cvt_pkrtz); permute into 16x16x32 B-frag
    unsigned int W00 = pk2(e0, e1), W01 = pk2(e2, e3);
    unsigned int W10 = pk2(e4, e5), W11 = pk2(e6, e7);
    int srcA = li + 32 * (lg & 1);
    int srcB = srcA + 16;
    unsigned int a00 = __shfl(W00, srcA), a01 = __shfl(W01, srcA);
    unsigned int a10 = __shfl(W10, srcA), a11 = __shfl(W11, srcA);
    unsigned int b00 = __shfl(W00, srcB), b01 = __shfl(W01, srcB);
    unsigned int b10 = __shfl(W10, srcB), b11 = __shfl(W11, srcB);
    bool h2 = (lg >> 1) != 0;
    union { unsigned int u[4]; f16x8 v; } pu;
    pu.u[0] = h2 ? a10 : a00;
    pu.u[1] = h2 ? a11 : a01;
    pu.u[2] = h2 ? b10 : b00;
    pu.u[3] = h2 ? b11 : b01;

    // PV: acc[ct] += V_tile * P^T
    __builtin_amdgcn_s_setprio(1);
    #pragma unroll
    for (int ct = 0; ct < 16; ++ct) {
      int c = ct * 16 + li;
      int off = c * 64 + ((lg ^ ((c >> 1) & 3)) * 16);
      f16x8 vf = *(const f16x8*)(bb + VOFF + off);
      acc[ct] = mfmah(vf, pu.v, acc[ct]);
    }
    __builtin_amdgcn_s_setprio(0);

    cur ^= 1;
  }

  // epilogue: normalize and store out[b][c][n] fp32
  float inv = 1.0f / l_run;
  #pragma unroll
  for (int ct = 0; ct < 16; ++ct) {
    #pragma unroll
    for (int r = 0; r < 4; ++r) {
      int c = ct * 16 + lg * 4 + r;
      out[((size_t)b * C_DIM + c) * N_DIM + q0 + li] = acc[ct][r] * inv;
    }
  }
#undef STAGE
}

extern "C" void kernel_launch(void* const* d_in, const int* in_sizes, int n_in,
                              void* d_out, int out_size, void* d_ws, size_t ws_size,
                              hipStream_t stream) {
  const float* x1 = (const float*)d_in[0];
  const float* x2 = (const float*)d_in[1];
  const float* Wq = (const float*)d_in[2];
  const float* bq = (const float*)d_in[3];
  const float* Wk = (const float*)d_in[4];
  const float* bk = (const float*)d_in[5];
  const float* Wv = (const float*)d_in[6];
  const float* bv = (const float*)d_in[7];
  float* out = (float*)d_out;

  char* ws = (char*)d_ws;
  const size_t SZ = (size_t)8 * 4096 * 256 * 2;  // 16.78 MB per fp16 plane
  _Float16* qt  = (_Float16*)(ws + 0 * SZ);
  _Float16* kt  = (_Float16*)(ws + 1 * SZ);
  _Float16* vv  = (_Float16*)(ws + 2 * SZ);
  _Float16* wsp = (_Float16*)(ws + 3 * SZ);  // 3*65536 fp16 = 384KB
  // requires ws_size >= 3*SZ + 393216 = 50,724,864 bytes

  cvt_w3<<<dim3(256, 3), 256, 0, stream>>>(Wq, Wk, Wv, wsp);
  proj_kernel<<<dim3(64, 8, 3), 256, 0, stream>>>(x1, x2, wsp, bq, bk, bv,
                                                  qt, kt, vv);
  attn_kernel<<<dim3(8, 32), 512, 0, stream>>>(qt, kt, vv, out);
}